// Round 4
// baseline (642.522 us; speedup 1.0000x reference)
//
#include <hip/hip_runtime.h>

#define Bsz 256
#define Ssz 2048
#define Isz 32
#define Hsz 18
#define SCALE 2.885390081777927f   // 2*log2(e): pre-scales all pre-activations

typedef float f2 __attribute__((ext_vector_type(2)));
typedef float f4 __attribute__((ext_vector_type(4)));

#define LO2(v) __builtin_shufflevector(v, v, 0, 1)
#define HI2(v) __builtin_shufflevector(v, v, 2, 3)

__device__ __forceinline__ float exp2_fast(float x) {
#if __has_builtin(__builtin_amdgcn_exp2f)
    return __builtin_amdgcn_exp2f(x);
#else
    return __expf(x * 0.6931471805599453f);
#endif
}

// K1: xw0T[b][i][t] = SCALE * (sum_k input[b][t][k]*Wih0[i][k] + bih0[i] + bhh0[i])
__global__ __launch_bounds__(256) void input_gemm(
    const float* __restrict__ x,
    const float* __restrict__ Wih0,
    const float* __restrict__ bih0,
    const float* __restrict__ bhh0,
    float* __restrict__ xw0T)
{
    __shared__ float xs[256 * 33];
    int blk = blockIdx.x;                  // 2048 blocks
    int b = blk >> 3;
    int t0 = (blk & 7) << 8;
    int tid = threadIdx.x;

    const float4* src = (const float4*)(x + ((size_t)b * Ssz + t0) * Isz);
#pragma unroll
    for (int k = 0; k < 8; ++k) {
        int l = k * 256 + tid;             // coalesced float4 index
        float4 v = src[l];
        int row = l >> 3, k4 = l & 7;
        float* p = xs + row * 33 + k4 * 4;
        p[0] = v.x; p[1] = v.y; p[2] = v.z; p[3] = v.w;
    }
    __syncthreads();

    float xv[32];
    const float* myrow = xs + tid * 33;
#pragma unroll
    for (int k = 0; k < 32; ++k) xv[k] = myrow[k];

    float* op = xw0T + (size_t)b * (Hsz * Ssz) + (t0 + tid);
#pragma unroll
    for (int ii = 0; ii < Hsz; ++ii) {
        float acc = bih0[ii] + bhh0[ii];
#pragma unroll
        for (int k = 0; k < 32; ++k) acc = fmaf(xv[k], Wih0[ii * Isz + k], acc);
        op[(size_t)ii * Ssz] = acc * SCALE;
    }
}

// K2: pipelined 3-layer scan, TWO batches per wave (time-multiplexed).
// Lane r = 18*g + i owns (layer g, unit i) for BOTH batches; batch B's LDS
// reads issue behind batch A's and their latency hides under A's compute.
// DS pipe is in-order per wave -> no sync needed beyond compiler fences.
__global__ __launch_bounds__(64) void rnn_scan(
    const float* __restrict__ xw0T,
    const float* __restrict__ hidden,
    const float* __restrict__ Whh0,
    const float* __restrict__ Wih1, const float* __restrict__ bih1,
    const float* __restrict__ Whh1, const float* __restrict__ bhh1,
    const float* __restrict__ Wih2, const float* __restrict__ bih2,
    const float* __restrict__ Whh2, const float* __restrict__ bhh2,
    float* __restrict__ h2T,
    float* __restrict__ hid_out)
{
    const int bp = blockIdx.x;           // 128 blocks
    const int b0 = bp * 2, b1 = b0 + 1;
    const int r = threadIdx.x;
    const int g = (r < 18) ? 0 : (r < 36) ? 1 : (r < 54) ? 2 : 3;
    const int i = r - g * 18;
    const bool lane_active = (g < 3);
    const bool g0lane = (g == 0);
    const bool g2lane = (g == 2);

    // Two independent 176-float exchange regions (A at 0, B at 192).
    __shared__ __align__(16) float sbuf[384];
    for (int k = r; k < 384; k += 64) sbuf[k] = 0.0f;
    float* sbufA = sbuf;
    float* sbufB = sbuf + 192;

    float wx[Hsz], wh[Hsz];
    float econst = 0.0f;
    float hA = 0.0f, hB = 0.0f;
    if (lane_active) {
        const float* Whh = (g == 0) ? Whh0 : (g == 1) ? Whh1 : Whh2;
#pragma unroll
        for (int j = 0; j < Hsz; ++j) wh[j] = Whh[i * Hsz + j] * SCALE;
        if (g >= 1) {
            const float* Wih = (g == 1) ? Wih1 : Wih2;
            const float* bi  = (g == 1) ? bih1 : bih2;
            const float* bh  = (g == 1) ? bhh1 : bhh2;
#pragma unroll
            for (int j = 0; j < Hsz; ++j) wx[j] = Wih[i * Hsz + j] * SCALE;
            econst = (bi[i] + bh[i]) * SCALE;
        } else {
#pragma unroll
            for (int j = 0; j < Hsz; ++j) wx[j] = 0.0f;
        }
        hA = hidden[(g * Bsz + b0) * Hsz + i];
        hB = hidden[(g * Bsz + b1) * Hsz + i];
    } else {
#pragma unroll
        for (int j = 0; j < Hsz; ++j) { wx[j] = 0.0f; wh[j] = 0.0f; }
    }

    f2 wx2[9], wh2[9];
#pragma unroll
    for (int k = 0; k < 9; ++k) {
        wx2[k] = f2{wx[2 * k], wx[2 * k + 1]};
        wh2[k] = f2{wh[2 * k], wh[2 * k + 1]};
    }

    const int slot  = 36 + 36 * g + i;   // g==3 dump region stays harmless
    const int xbase = 36 * g;            // previous group's state
    const int hbase = 36 * g + 36;       // own group's state

    sbufA[slot] = hA;
    sbufB[slot] = hB;
    __builtin_amdgcn_wave_barrier();

    const float* xwpA = xw0T + (size_t)b0 * (Hsz * Ssz) + (size_t)((g == 0) ? i : 0) * Ssz;
    const float* xwpB = xw0T + (size_t)b1 * (Hsz * Ssz) + (size_t)((g == 0) ? i : 0) * Ssz;
    float*       hopA = h2T + (size_t)b0 * (Hsz * Ssz) + (size_t)i * Ssz; // g2 only
    float*       hopB = h2T + (size_t)b1 * (Hsz * Ssz) + (size_t)i * Ssz;

    const f4* sx4A = (const f4*)(sbufA + xbase);
    const f4* sh4A = (const f4*)(sbufA + hbase);
    const f2* sx2A = (const f2*)(sbufA + xbase + 16);
    const f2* sh2A = (const f2*)(sbufA + hbase + 16);
    const f4* sx4B = (const f4*)(sbufB + xbase);
    const f4* sh4B = (const f4*)(sbufB + hbase);
    const f2* sx2B = (const f2*)(sbufB + xbase + 16);
    const f2* sh2B = (const f2*)(sbufB + hbase + 16);

    f4 curA = *(const f4*)(xwpA + 0), nxtA = *(const f4*)(xwpA + 4);
    f4 curB = *(const f4*)(xwpB + 0), nxtB = *(const f4*)(xwpB + 4);
    f4 obA, obB;

    auto dot_tanh = [&](float e, f4 qa, f4 qb, f4 qc, f4 qd, f2 qe,
                                 f4 pa, f4 pb, f4 pc, f4 pd, f2 pe) -> float {
        f2 ax0 = f2{e, 0.0f}, ax1 = f2{0.0f, 0.0f}, ax2 = f2{0.0f, 0.0f};
        f2 ah0 = f2{0.0f, 0.0f}, ah1 = f2{0.0f, 0.0f}, ah2 = f2{0.0f, 0.0f};
        ax0 = __builtin_elementwise_fma(wx2[0], LO2(qa), ax0);
        ax1 = __builtin_elementwise_fma(wx2[1], HI2(qa), ax1);
        ax2 = __builtin_elementwise_fma(wx2[2], LO2(qb), ax2);
        ah0 = __builtin_elementwise_fma(wh2[0], LO2(pa), ah0);
        ah1 = __builtin_elementwise_fma(wh2[1], HI2(pa), ah1);
        ah2 = __builtin_elementwise_fma(wh2[2], LO2(pb), ah2);
        ax0 = __builtin_elementwise_fma(wx2[3], HI2(qb), ax0);
        ax1 = __builtin_elementwise_fma(wx2[4], LO2(qc), ax1);
        ax2 = __builtin_elementwise_fma(wx2[5], HI2(qc), ax2);
        ah0 = __builtin_elementwise_fma(wh2[3], HI2(pb), ah0);
        ah1 = __builtin_elementwise_fma(wh2[4], LO2(pc), ah1);
        ah2 = __builtin_elementwise_fma(wh2[5], HI2(pc), ah2);
        ax0 = __builtin_elementwise_fma(wx2[6], LO2(qd), ax0);
        ax1 = __builtin_elementwise_fma(wx2[7], HI2(qd), ax1);
        ax2 = __builtin_elementwise_fma(wx2[8], qe,      ax2);
        ah0 = __builtin_elementwise_fma(wh2[6], LO2(pd), ah0);
        ah1 = __builtin_elementwise_fma(wh2[7], HI2(pd), ah1);
        ah2 = __builtin_elementwise_fma(wh2[8], pe,      ah2);
        f2 t0 = ax0 + ax1, t1 = ax2 + ah0, t2 = ah1 + ah2;
        f2 s = (t0 + t1) + t2;
        float a = s.x + s.y;
        float t = exp2_fast(a);
        return fmaf(-2.0f, __builtin_amdgcn_rcpf(t + 1.0f), 1.0f);
    };

    // One tick for both batches. All 20 reads issue first (A's, then B's);
    // B's latency hides under A's dot+tanh. use_mask/upd applied to both.
    auto do_tick = [&](float eA, float eB, bool use_mask, bool upd,
                       bool dostore, int st) {
        f4 qa0 = sx4A[0], qb0 = sx4A[1], qc0 = sx4A[2], qd0 = sx4A[3];
        f2 qe0 = sx2A[0];
        f4 pa0 = sh4A[0], pb0 = sh4A[1], pc0 = sh4A[2], pd0 = sh4A[3];
        f2 pe0 = sh2A[0];
        f4 qa1 = sx4B[0], qb1 = sx4B[1], qc1 = sx4B[2], qd1 = sx4B[3];
        f2 qe1 = sx2B[0];
        f4 pa1 = sh4B[0], pb1 = sh4B[1], pc1 = sh4B[2], pd1 = sh4B[3];
        f2 pe1 = sh2B[0];
        if (dostore && g2lane) {              // off the dep chain
            *(f4*)(hopA + st) = obA;
            *(f4*)(hopB + st) = obB;
        }
        float nhA = dot_tanh(eA, qa0, qb0, qc0, qd0, qe0, pa0, pb0, pc0, pd0, pe0);
        hA = use_mask ? (upd ? nhA : hA) : nhA;
        sbufA[slot] = hA;
        float nhB = dot_tanh(eB, qa1, qb1, qc1, qd1, qe1, pa1, pb1, pc1, pd1, pe1);
        hB = use_mask ? (upd ? nhB : hB) : nhB;
        sbufB[slot] = hB;
        __builtin_amdgcn_wave_barrier();
    };

    // ---- prologue: T = 0..3, masked updates, no store ----
    {
        f4 futA = *(const f4*)(xwpA + 8);
        f4 futB = *(const f4*)(xwpB + 8);
        float evA[4] = {curA.x, curA.y, curA.z, curA.w};
        float evB[4] = {curB.x, curB.y, curB.z, curB.w};
#pragma unroll
        for (int u = 0; u < 4; ++u) {
            const int T = u;
            float eA = g0lane ? evA[u] : econst;
            float eB = g0lane ? evB[u] : econst;
            bool upd = lane_active && (T >= g);
            do_tick(eA, eB, true, upd, false, 0);
            if (u == 2) { obA.x = hA; obB.x = hB; }
            else if (u == 3) { obA.y = hA; obB.y = hB; }
        }
        curA = nxtA; nxtA = futA;
        curB = nxtB; nxtB = futB;
    }

    // ---- interior: T = 4..2047, unmasked; flush quad (tb-4..tb-1) at u==2 ----
    for (int tb = 4; tb < Ssz; tb += 4) {
        int tl = tb + 8; if (tl > Ssz - 4) tl = Ssz - 4;
        f4 futA = *(const f4*)(xwpA + tl);
        f4 futB = *(const f4*)(xwpB + tl);
        float evA[4] = {curA.x, curA.y, curA.z, curA.w};
        float evB[4] = {curB.x, curB.y, curB.z, curB.w};
#pragma unroll
        for (int u = 0; u < 4; ++u) {
            float eA = g0lane ? evA[u] : econst;
            float eB = g0lane ? evB[u] : econst;
            do_tick(eA, eB, false, false, u == 2, tb - 4);
            if (u == 0)      { obA.z = hA; obB.z = hB; }
            else if (u == 1) { obA.w = hA; obB.w = hB; }
            else if (u == 2) { obA.x = hA; obB.x = hB; }
            else             { obA.y = hA; obB.y = hB; }
        }
        curA = nxtA; nxtA = futA;
        curB = nxtB; nxtB = futB;
    }

    // ---- tail: T = 2048..2049, masked (freeze finished groups) ----
    {
        float evA[4] = {curA.x, curA.y, curA.z, curA.w};
        float evB[4] = {curB.x, curB.y, curB.z, curB.w};
#pragma unroll
        for (int u = 0; u < 2; ++u) {
            const int T = Ssz + u;
            float eA = g0lane ? evA[u] : econst;
            float eB = g0lane ? evB[u] : econst;
            bool upd = lane_active && (T <= Ssz - 1 + g);
            do_tick(eA, eB, true, upd, false, 0);
            if (u == 0) { obA.z = hA; obB.z = hB; }
            else        { obA.w = hA; obB.w = hB; }
        }
        if (g2lane) {
            *(f4*)(hopA + Ssz - 4) = obA;   // final quad t=2044..2047
            *(f4*)(hopB + Ssz - 4) = obB;
        }
    }

    if (lane_active) {
        hid_out[(g * Bsz + b0) * Hsz + i] = hA;
        hid_out[(g * Bsz + b1) * Hsz + i] = hB;
    }
}

// K3: MLP head 18->18->10->8->4->2->1, one thread per (b,t).
__global__ __launch_bounds__(256) void mlp_head(
    const float* __restrict__ h2T,
    const float* __restrict__ W1, const float* __restrict__ b1,
    const float* __restrict__ W2, const float* __restrict__ b2,
    const float* __restrict__ W3, const float* __restrict__ b3,
    const float* __restrict__ W4, const float* __restrict__ b4,
    const float* __restrict__ W5, const float* __restrict__ b5,
    const float* __restrict__ W6, const float* __restrict__ b6,
    float* __restrict__ out)
{
    int idx = blockIdx.x * 256 + threadIdx.x;  // = b*S + t
    int b = idx >> 11;
    int t = idx & (Ssz - 1);
    const float* hp = h2T + (size_t)b * (Hsz * Ssz) + t;
    float v[Hsz];
#pragma unroll
    for (int j = 0; j < Hsz; ++j) v[j] = hp[(size_t)j * Ssz];

    float a1[18];
#pragma unroll
    for (int o = 0; o < 18; ++o) {
        float acc = b1[o];
#pragma unroll
        for (int j = 0; j < 18; ++j) acc = fmaf(W1[o * 18 + j], v[j], acc);
        a1[o] = fmaxf(acc, 0.0f);
    }
    float a2[10];
#pragma unroll
    for (int o = 0; o < 10; ++o) {
        float acc = b2[o];
#pragma unroll
        for (int j = 0; j < 18; ++j) acc = fmaf(W2[o * 18 + j], a1[j], acc);
        a2[o] = fmaxf(acc, 0.0f);
    }
    float a3[8];
#pragma unroll
    for (int o = 0; o < 8; ++o) {
        float acc = b3[o];
#pragma unroll
        for (int j = 0; j < 10; ++j) acc = fmaf(W3[o * 10 + j], a2[j], acc);
        a3[o] = fmaxf(acc, 0.0f);
    }
    float a4[4];
#pragma unroll
    for (int o = 0; o < 4; ++o) {
        float acc = b4[o];
#pragma unroll
        for (int j = 0; j < 8; ++j) acc = fmaf(W4[o * 8 + j], a3[j], acc);
        a4[o] = fmaxf(acc, 0.0f);
    }
    float a5[2];
#pragma unroll
    for (int o = 0; o < 2; ++o) {
        float acc = b5[o];
#pragma unroll
        for (int j = 0; j < 4; ++j) acc = fmaf(W5[o * 4 + j], a4[j], acc);
        a5[o] = fmaxf(acc, 0.0f);
    }
    float r6 = b6[0];
    r6 = fmaf(W6[0], a5[0], r6);
    r6 = fmaf(W6[1], a5[1], r6);
    out[idx] = r6;
}

extern "C" void kernel_launch(void* const* d_in, const int* in_sizes, int n_in,
                              void* d_out, int out_size, void* d_ws, size_t ws_size,
                              hipStream_t stream) {
    (void)in_sizes; (void)n_in; (void)out_size; (void)ws_size;
    const float* input  = (const float*)d_in[0];
    const float* hidden = (const float*)d_in[1];
    const float* Wih0 = (const float*)d_in[2];  const float* bih0 = (const float*)d_in[3];
    const float* Whh0 = (const float*)d_in[4];  const float* bhh0 = (const float*)d_in[5];
    const float* Wih1 = (const float*)d_in[6];  const float* bih1 = (const float*)d_in[7];
    const float* Whh1 = (const float*)d_in[8];  const float* bhh1 = (const float*)d_in[9];
    const float* Wih2 = (const float*)d_in[10]; const float* bih2 = (const float*)d_in[11];
    const float* Whh2 = (const float*)d_in[12]; const float* bhh2 = (const float*)d_in[13];
    const float* W1 = (const float*)d_in[14]; const float* b1 = (const float*)d_in[15];
    const float* W2 = (const float*)d_in[16]; const float* b2 = (const float*)d_in[17];
    const float* W3 = (const float*)d_in[18]; const float* b3 = (const float*)d_in[19];
    const float* W4 = (const float*)d_in[20]; const float* b4 = (const float*)d_in[21];
    const float* W5 = (const float*)d_in[22]; const float* b5 = (const float*)d_in[23];
    const float* W6 = (const float*)d_in[24]; const float* b6 = (const float*)d_in[25];

    float* xw0T = (float*)d_ws;                         // [B][18][S]
    float* h2T  = xw0T + (size_t)Bsz * Hsz * Ssz;       // [B][18][S]
    float* out  = (float*)d_out;                        // [B*S]
    float* hout = out + (size_t)Bsz * Ssz;              // [3][B][18]

    input_gemm<<<dim3(2048), dim3(256), 0, stream>>>(input, Wih0, bih0, bhh0, xw0T);
    rnn_scan<<<dim3(128), dim3(64), 0, stream>>>(xw0T, hidden, Whh0,
                                                 Wih1, bih1, Whh1, bhh1,
                                                 Wih2, bih2, Whh2, bhh2,
                                                 h2T, hout);
    mlp_head<<<dim3(2048), dim3(256), 0, stream>>>(h2T, W1, b1, W2, b2, W3, b3,
                                                   W4, b4, W5, b5, W6, b6, out);
}

// Round 5
// 455.910 us; speedup vs baseline: 1.4093x; 1.4093x over previous
//
#include <hip/hip_runtime.h>

#define Bsz 256
#define Ssz 2048
#define Isz 32
#define Hsz 18
#define SCALE 2.885390081777927f   // 2*log2(e): pre-scales all pre-activations

typedef float f2 __attribute__((ext_vector_type(2)));
typedef float f4 __attribute__((ext_vector_type(4)));

#define LO2(v) __builtin_shufflevector(v, v, 0, 1)
#define HI2(v) __builtin_shufflevector(v, v, 2, 3)

__device__ __forceinline__ float exp2_fast(float x) {
#if __has_builtin(__builtin_amdgcn_exp2f)
    return __builtin_amdgcn_exp2f(x);
#else
    return __expf(x * 0.6931471805599453f);
#endif
}

// K1: xw0T[b][i][t] = SCALE * (sum_k input[b][t][k]*Wih0[i][k] + bih0[i] + bhh0[i])
__global__ __launch_bounds__(256) void input_gemm(
    const float* __restrict__ x,
    const float* __restrict__ Wih0,
    const float* __restrict__ bih0,
    const float* __restrict__ bhh0,
    float* __restrict__ xw0T)
{
    __shared__ float xs[256 * 33];
    int blk = blockIdx.x;                  // 2048 blocks
    int b = blk >> 3;
    int t0 = (blk & 7) << 8;
    int tid = threadIdx.x;

    const float4* src = (const float4*)(x + ((size_t)b * Ssz + t0) * Isz);
#pragma unroll
    for (int k = 0; k < 8; ++k) {
        int l = k * 256 + tid;             // coalesced float4 index
        float4 v = src[l];
        int row = l >> 3, k4 = l & 7;
        float* p = xs + row * 33 + k4 * 4;
        p[0] = v.x; p[1] = v.y; p[2] = v.z; p[3] = v.w;
    }
    __syncthreads();

    float xv[32];
    const float* myrow = xs + tid * 33;
#pragma unroll
    for (int k = 0; k < 32; ++k) xv[k] = myrow[k];

    float* op = xw0T + (size_t)b * (Hsz * Ssz) + (t0 + tid);
#pragma unroll
    for (int ii = 0; ii < Hsz; ++ii) {
        float acc = bih0[ii] + bhh0[ii];
#pragma unroll
        for (int k = 0; k < 32; ++k) acc = fmaf(xv[k], Wih0[ii * Isz + k], acc);
        op[(size_t)ii * Ssz] = acc * SCALE;
    }
}

// K2: pipelined 3-layer scan as a 54-wide recurrence. ONE batch per wave
// (256 waves run in parallel; wall time = per-tick chain latency * 2050).
// Lane r = 18*g + i owns (layer g, unit i); group g at tick T computes
// h_g[t = T - g].
//
// State buffer X (double-write layout): X[36g .. 36g+17] = state of group
// g-1, X[36g+18 .. 36g+35] = state of group g. Each lane writes h to
// X[36g+18+i] (own slot) and X[36(g+1)+i] (next group's prev slot), so every
// lane reads its full 36-float operand window as 9 aligned ds_read_b128
// from ONE base pointer with immediate offsets.
__global__ __launch_bounds__(64) void rnn_scan(
    const float* __restrict__ xw0T,
    const float* __restrict__ hidden,
    const float* __restrict__ Whh0,
    const float* __restrict__ Wih1, const float* __restrict__ bih1,
    const float* __restrict__ Whh1, const float* __restrict__ bhh1,
    const float* __restrict__ Wih2, const float* __restrict__ bih2,
    const float* __restrict__ Whh2, const float* __restrict__ bhh2,
    float* __restrict__ h2T,
    float* __restrict__ hid_out)
{
    const int b = blockIdx.x;
    const int r = threadIdx.x;
    const int g = (r < 18) ? 0 : (r < 36) ? 1 : (r < 54) ? 2 : 3;
    const int i = r - g * 18;
    const bool lane_active = (g < 3);
    const bool g0lane = (g == 0);
    const bool g2lane = (g == 2);

    __shared__ __align__(16) float X[192];
    for (int k = r; k < 192; k += 64) X[k] = 0.0f;
    __builtin_amdgcn_wave_barrier();

    // Combined per-lane weight row: w[0..17] = Wih (prev-state), w[18..35] = Whh.
    float w[36];
    float econst = 0.0f;
    float h = 0.0f;
    if (lane_active) {
        const float* Whh = (g == 0) ? Whh0 : (g == 1) ? Whh1 : Whh2;
#pragma unroll
        for (int j = 0; j < Hsz; ++j) w[18 + j] = Whh[i * Hsz + j] * SCALE;
        if (g >= 1) {
            const float* Wih = (g == 1) ? Wih1 : Wih2;
            const float* bi  = (g == 1) ? bih1 : bih2;
            const float* bh  = (g == 1) ? bhh1 : bhh2;
#pragma unroll
            for (int j = 0; j < Hsz; ++j) w[j] = Wih[i * Hsz + j] * SCALE;
            econst = (bi[i] + bh[i]) * SCALE;
        } else {
#pragma unroll
            for (int j = 0; j < Hsz; ++j) w[j] = 0.0f;   // g0: x-window is zeros
        }
        h = hidden[(g * Bsz + b) * Hsz + i];
    } else {
#pragma unroll
        for (int j = 0; j < 36; ++j) w[j] = 0.0f;
    }

    f4 w4[9];
#pragma unroll
    for (int k = 0; k < 9; ++k) w4[k] = f4{w[4*k], w[4*k+1], w[4*k+2], w[4*k+3]};

    const int slotW = 36 * g + 18 + i;    // own slot; +18 = next group's prev slot
    const f4* xr = (const f4*)(X + 36 * g);

    X[slotW] = h;
    X[slotW + 18] = h;
    __builtin_amdgcn_wave_barrier();

    const float* xwp = xw0T + (size_t)b * (Hsz * Ssz) + (size_t)((g == 0) ? i : 0) * Ssz;
    float*       hop2 = h2T + (size_t)b * (Hsz * Ssz) + (size_t)i * Ssz; // g2 only

    f4 cur = *(const f4*)(xwp + 0);
    f4 nxt = *(const f4*)(xwp + 4);
    f4 ob;  // g2 output quad; slot for t is ob[t&3]

    // dot+tanh on the 9-f4 window; acc init carries e.
    auto dot_tanh = [&](float e, const f4* v) -> float {
        f4 a0 = f4{e, 0.0f, 0.0f, 0.0f};
        f4 a1 = f4{0.0f, 0.0f, 0.0f, 0.0f};
        f4 a2 = f4{0.0f, 0.0f, 0.0f, 0.0f};
        a0 = __builtin_elementwise_fma(w4[0], v[0], a0);
        a1 = __builtin_elementwise_fma(w4[1], v[1], a1);
        a2 = __builtin_elementwise_fma(w4[2], v[2], a2);
        a0 = __builtin_elementwise_fma(w4[3], v[3], a0);
        a1 = __builtin_elementwise_fma(w4[4], v[4], a1);
        a2 = __builtin_elementwise_fma(w4[5], v[5], a2);
        a0 = __builtin_elementwise_fma(w4[6], v[6], a0);
        a1 = __builtin_elementwise_fma(w4[7], v[7], a1);
        a2 = __builtin_elementwise_fma(w4[8], v[8], a2);
        f4 s = (a0 + a1) + a2;
        f2 s2 = LO2(s) + HI2(s);
        float a = s2.x + s2.y;
        float t = exp2_fast(a);
        return fmaf(-2.0f, __builtin_amdgcn_rcpf(t + 1.0f), 1.0f);
    };

    // ---- prologue: T = 0..3, masked updates, no store ----
    {
        f4 fut = *(const f4*)(xwp + 8);
        float ev[4] = {cur.x, cur.y, cur.z, cur.w};
#pragma unroll
        for (int u = 0; u < 4; ++u) {
            const int T = u;
            f4 v0 = xr[0], v1 = xr[1], v2 = xr[2], v3 = xr[3], v4 = xr[4],
               v5 = xr[5], v6 = xr[6], v7 = xr[7], v8 = xr[8];
            f4 vv[9] = {v0, v1, v2, v3, v4, v5, v6, v7, v8};
            float e = g0lane ? ev[u] : econst;
            float nh = dot_tanh(e, vv);
            bool upd = lane_active && (T >= g);
            h = upd ? nh : h;
            X[slotW] = h;
            X[slotW + 18] = h;
            if (u == 2) ob.x = h; else if (u == 3) ob.y = h;
            __builtin_amdgcn_wave_barrier();
        }
        cur = nxt; nxt = fut;
    }

    // ---- interior: T = 4..2047, unmasked; g2 flushes quad (tb-4..tb-1) at u==2 ----
    for (int tb = 4; tb < Ssz; tb += 4) {
        int tl = tb + 8; if (tl > Ssz - 4) tl = Ssz - 4;
        f4 fut = *(const f4*)(xwp + tl);
#pragma unroll
        for (int u = 0; u < 4; ++u) {
            f4 v0 = xr[0], v1 = xr[1], v2 = xr[2], v3 = xr[3], v4 = xr[4],
               v5 = xr[5], v6 = xr[6], v7 = xr[7], v8 = xr[8];
            if (u == 2 && g2lane) *(f4*)(hop2 + tb - 4) = ob;  // off the dep chain
            f4 vv[9] = {v0, v1, v2, v3, v4, v5, v6, v7, v8};
            float e = g0lane ? ((u == 0) ? cur.x : (u == 1) ? cur.y
                               : (u == 2) ? cur.z : cur.w)
                             : econst;
            h = dot_tanh(e, vv);     // idle lanes: tanh(0)=0, harmless
            X[slotW] = h;
            X[slotW + 18] = h;
            if (u == 0) ob.z = h;
            else if (u == 1) ob.w = h;
            else if (u == 2) ob.x = h;
            else ob.y = h;
            __builtin_amdgcn_wave_barrier();
        }
        cur = nxt; nxt = fut;
    }

    // ---- tail: T = 2048..2049, masked (freeze finished groups) ----
    {
        float ev[2] = {cur.x, cur.y};
#pragma unroll
        for (int u = 0; u < 2; ++u) {
            const int T = Ssz + u;
            f4 v0 = xr[0], v1 = xr[1], v2 = xr[2], v3 = xr[3], v4 = xr[4],
               v5 = xr[5], v6 = xr[6], v7 = xr[7], v8 = xr[8];
            f4 vv[9] = {v0, v1, v2, v3, v4, v5, v6, v7, v8};
            float e = g0lane ? ev[u] : econst;
            float nh = dot_tanh(e, vv);
            bool upd = lane_active && (T <= Ssz - 1 + g);
            h = upd ? nh : h;
            X[slotW] = h;
            X[slotW + 18] = h;
            if (u == 0) ob.z = h; else ob.w = h;
            __builtin_amdgcn_wave_barrier();
        }
        if (g2lane) *(f4*)(hop2 + Ssz - 4) = ob;  // final quad t=2044..2047
    }

    if (lane_active) hid_out[(g * Bsz + b) * Hsz + i] = h;
}

// K3: MLP head 18->18->10->8->4->2->1, one thread per (b,t).
__global__ __launch_bounds__(256) void mlp_head(
    const float* __restrict__ h2T,
    const float* __restrict__ W1, const float* __restrict__ b1,
    const float* __restrict__ W2, const float* __restrict__ b2,
    const float* __restrict__ W3, const float* __restrict__ b3,
    const float* __restrict__ W4, const float* __restrict__ b4,
    const float* __restrict__ W5, const float* __restrict__ b5,
    const float* __restrict__ W6, const float* __restrict__ b6,
    float* __restrict__ out)
{
    int idx = blockIdx.x * 256 + threadIdx.x;  // = b*S + t
    int b = idx >> 11;
    int t = idx & (Ssz - 1);
    const float* hp = h2T + (size_t)b * (Hsz * Ssz) + t;
    float v[Hsz];
#pragma unroll
    for (int j = 0; j < Hsz; ++j) v[j] = hp[(size_t)j * Ssz];

    float a1[18];
#pragma unroll
    for (int o = 0; o < 18; ++o) {
        float acc = b1[o];
#pragma unroll
        for (int j = 0; j < 18; ++j) acc = fmaf(W1[o * 18 + j], v[j], acc);
        a1[o] = fmaxf(acc, 0.0f);
    }
    float a2[10];
#pragma unroll
    for (int o = 0; o < 10; ++o) {
        float acc = b2[o];
#pragma unroll
        for (int j = 0; j < 18; ++j) acc = fmaf(W2[o * 18 + j], a1[j], acc);
        a2[o] = fmaxf(acc, 0.0f);
    }
    float a3[8];
#pragma unroll
    for (int o = 0; o < 8; ++o) {
        float acc = b3[o];
#pragma unroll
        for (int j = 0; j < 10; ++j) acc = fmaf(W3[o * 10 + j], a2[j], acc);
        a3[o] = fmaxf(acc, 0.0f);
    }
    float a4[4];
#pragma unroll
    for (int o = 0; o < 4; ++o) {
        float acc = b4[o];
#pragma unroll
        for (int j = 0; j < 8; ++j) acc = fmaf(W4[o * 8 + j], a3[j], acc);
        a4[o] = fmaxf(acc, 0.0f);
    }
    float a5[2];
#pragma unroll
    for (int o = 0; o < 2; ++o) {
        float acc = b5[o];
#pragma unroll
        for (int j = 0; j < 4; ++j) acc = fmaf(W5[o * 4 + j], a4[j], acc);
        a5[o] = fmaxf(acc, 0.0f);
    }
    float r6 = b6[0];
    r6 = fmaf(W6[0], a5[0], r6);
    r6 = fmaf(W6[1], a5[1], r6);
    out[idx] = r6;
}

extern "C" void kernel_launch(void* const* d_in, const int* in_sizes, int n_in,
                              void* d_out, int out_size, void* d_ws, size_t ws_size,
                              hipStream_t stream) {
    (void)in_sizes; (void)n_in; (void)out_size; (void)ws_size;
    const float* input  = (const float*)d_in[0];
    const float* hidden = (const float*)d_in[1];
    const float* Wih0 = (const float*)d_in[2];  const float* bih0 = (const float*)d_in[3];
    const float* Whh0 = (const float*)d_in[4];  const float* bhh0 = (const float*)d_in[5];
    const float* Wih1 = (const float*)d_in[6];  const float* bih1 = (const float*)d_in[7];
    const float* Whh1 = (const float*)d_in[8];  const float* bhh1 = (const float*)d_in[9];
    const float* Wih2 = (const float*)d_in[10]; const float* bih2 = (const float*)d_in[11];
    const float* Whh2 = (const float*)d_in[12]; const float* bhh2 = (const float*)d_in[13];
    const float* W1 = (const float*)d_in[14]; const float* b1 = (const float*)d_in[15];
    const float* W2 = (const float*)d_in[16]; const float* b2 = (const float*)d_in[17];
    const float* W3 = (const float*)d_in[18]; const float* b3 = (const float*)d_in[19];
    const float* W4 = (const float*)d_in[20]; const float* b4 = (const float*)d_in[21];
    const float* W5 = (const float*)d_in[22]; const float* b5 = (const float*)d_in[23];
    const float* W6 = (const float*)d_in[24]; const float* b6 = (const float*)d_in[25];

    float* xw0T = (float*)d_ws;                         // [B][18][S]
    float* h2T  = xw0T + (size_t)Bsz * Hsz * Ssz;       // [B][18][S]
    float* out  = (float*)d_out;                        // [B*S]
    float* hout = out + (size_t)Bsz * Ssz;              // [3][B][18]

    input_gemm<<<dim3(2048), dim3(256), 0, stream>>>(input, Wih0, bih0, bhh0, xw0T);
    rnn_scan<<<dim3(256), dim3(64), 0, stream>>>(xw0T, hidden, Whh0,
                                                 Wih1, bih1, Whh1, bhh1,
                                                 Wih2, bih2, Whh2, bhh2,
                                                 h2T, hout);
    mlp_head<<<dim3(2048), dim3(256), 0, stream>>>(h2T, W1, b1, W2, b2, W3, b3,
                                                   W4, b4, W5, b5, W6, b6, out);
}